// Round 7
// baseline (275.553 us; speedup 1.0000x reference)
//
#include <hip/hip_runtime.h>
#include <cstdint>
#include <cstddef>

// Problem: B=128, S=512, H=512
//   context[b,h] = sum_s softmax_s( sum_k tanh(u[b,s,k]) Ve[k] ) * h[b,s,h]
//   u = h@U1a^T + x@U2^T + (h_last@U1b^T broadcast over s)
// R7: R6 GEMM + double-buffered LDS with counted vmcnt (pure global_load_lds,
//   zero staging VGPRs -> first clean T4 test), fast tanh epilogue, and a
//   fused softmax+context kernel.

typedef _Float16 h8 __attribute__((ext_vector_type(8)));
typedef float    f4 __attribute__((ext_vector_type(4)));

#define GLOAD16(g, l)                                                          \
  __builtin_amdgcn_global_load_lds(                                            \
      (const __attribute__((address_space(1))) void*)(g),                      \
      (__attribute__((address_space(3))) void*)(l), 16, 0, 0)

__device__ __forceinline__ float fast_tanh(float v) {
  float ex = __expf(2.0f * v);          // v_exp_f32 path; inf/0 saturate correctly
  return 1.0f - 2.0f / (ex + 1.0f);
}

// ---------------------------------------------------------------------------
// Streaming f32 -> fp16 (row-major preserved). 8 elems / thread / iter.
// ---------------------------------------------------------------------------
__global__ __launch_bounds__(256)
void cvt_kernel(const float* __restrict__ src, _Float16* __restrict__ dst, int n8) {
  const int stride = gridDim.x * 256;
  for (int i = blockIdx.x * 256 + threadIdx.x; i < n8; i += stride) {
    const float* p = src + (size_t)i * 8;
    f4 a = *(const f4*)p, b = *(const f4*)(p + 4);
    _Float16 hv[8];
    hv[0]=(_Float16)a[0]; hv[1]=(_Float16)a[1]; hv[2]=(_Float16)a[2]; hv[3]=(_Float16)a[3];
    hv[4]=(_Float16)b[0]; hv[5]=(_Float16)b[1]; hv[6]=(_Float16)b[2]; hv[7]=(_Float16)b[3];
    *(uint4*)(dst + (size_t)i * 8) = *(uint4*)hv;
  }
}

// ---------------------------------------------------------------------------
// B image, FRAGMENT-ORDERED: chunk g = [nt(4)][kt(16)][s(8)][grp(8)][l15(16)]
// chunk (16B) = U[nt*128 + grp*16 + l15][kt*64 + s*8 .. +8],
// U[n][k] = k<512 ? U1[n][k] : U2[n][k-512]
// ---------------------------------------------------------------------------
__global__ void bsetup2_kernel(const float* __restrict__ U1, const float* __restrict__ U2,
                               _Float16* __restrict__ Bimg) {
  int g = blockIdx.x * 256 + threadIdx.x;   // 65536 chunks
  int l15 = g & 15;
  int grp = (g >> 4) & 7;
  int s   = (g >> 7) & 7;
  int kt  = (g >> 10) & 15;
  int nt  = g >> 14;
  int n = nt * 128 + grp * 16 + l15;
  int k = kt * 64 + s * 8;
  const float* p = (k < 512) ? (U1 + (size_t)n * 1024 + k)
                             : (U2 + (size_t)n * 512 + (k - 512));
  f4 a = *(const f4*)p, b = *(const f4*)(p + 4);
  _Float16 hv[8];
  hv[0]=(_Float16)a[0]; hv[1]=(_Float16)a[1]; hv[2]=(_Float16)a[2]; hv[3]=(_Float16)a[3];
  hv[4]=(_Float16)b[0]; hv[5]=(_Float16)b[1]; hv[6]=(_Float16)b[2]; hv[7]=(_Float16)b[3];
  *(uint4*)(Bimg + (size_t)g * 8) = *(uint4*)hv;
}

// ---------------------------------------------------------------------------
// bias[b][n] = sum_h h[b][S-1][h] * U1[n][512+h]   (fp32, exact)
// ---------------------------------------------------------------------------
__global__ void bias_kernel(const float* __restrict__ hT, const float* __restrict__ U1,
                            float* __restrict__ bias) {
  const int b = blockIdx.x, t = threadIdx.x;
  const int l = t & 63, w = t >> 6;
  __shared__ float4 hl[128];
  if (t < 128) hl[t] = *(const float4*)(hT + ((size_t)b * 512 + 511) * 512 + t * 4);
  __syncthreads();
  for (int n = w; n < 512; n += 4) {
    const float4* ur = (const float4*)(U1 + (size_t)n * 1024 + 512);
    float4 u0 = ur[l],      u1 = ur[l + 64];
    float4 h0 = hl[l],      h1 = hl[l + 64];
    float s = u0.x*h0.x + u0.y*h0.y + u0.z*h0.z + u0.w*h0.w
            + u1.x*h1.x + u1.y*h1.y + u1.z*h1.z + u1.w*h1.w;
#pragma unroll
    for (int d = 1; d < 64; d <<= 1) s += __shfl_xor(s, d, 64);
    if (l == 0) bias[(size_t)b * 512 + n] = s;
  }
}

// ---------------------------------------------------------------------------
// Fused GEMM, double-buffered. M=65536, N=512, K=1024. BM=128 BN=128 BK=64.
// 4 waves (2x2), wave tile 64x64, 4x4 frags 16x16x32. All staging is
// global_load_lds; per-iter barriers: {lgkm0+bar} then {vmcnt(8)+bar}.
// Loads stay one full tile ahead -> latency hidden under compute.
// ---------------------------------------------------------------------------
__global__ __launch_bounds__(256, 2)
void gemm3_kernel(const _Float16* __restrict__ hF, const _Float16* __restrict__ xF,
                  const _Float16* __restrict__ Bimg, const float* __restrict__ bias,
                  const float* __restrict__ Ve, float* __restrict__ e) {
  const int bid  = ((int)blockIdx.x & 7) * 256 + ((int)blockIdx.x >> 3);
  const int bm   = bid >> 2;
  const int nt   = bid & 3;
  const int row0 = bm * 128;
  const int bb   = row0 >> 9;
  const int t    = threadIdx.x;
  const int l    = t & 63;
  const int wv   = t >> 6;
  const int wm   = wv >> 1, wn = wv & 1;
  const int l15  = l & 15, lhi = l >> 4;

  __shared__ __align__(16) _Float16 Asm[2][8192];   // 2 x 16 KB
  __shared__ __align__(16) _Float16 Bsm[2][8192];   // 2 x 16 KB

  // A DMA source offset (fp16 elems), XOR pre-swizzle baked in; dest linear.
  const int aoff0 = (wv * 32 + (l >> 3)) * 512 + (((l & 7) ^ (l >> 3)) << 3);

  auto STAGE = [&](int c, int kt) {     // 8 gload_lds per wave (4 A + 4 B)
    const _Float16* ah = ((kt < 8) ? hF : xF) + (size_t)row0 * 512 + (kt & 7) * 64;
#pragma unroll
    for (int j = 0; j < 4; ++j)
      GLOAD16(ah + aoff0 + j * 4096, &Asm[c][wv * 2048 + j * 512]);
    const _Float16* bt = Bimg + ((size_t)(nt * 16 + kt) << 13);
#pragma unroll
    for (int j = 0; j < 4; ++j)
      GLOAD16(bt + wv * 2048 + j * 512 + l * 8, &Bsm[c][wv * 2048 + j * 512]);
  };

  // Fragment read bases (fp16-elem offsets), computed once.
  const int vA0 = wm * 4096 + l15 * 64 + (((0 + lhi) ^ (l15 & 7)) << 3);
  const int vA1 = wm * 4096 + l15 * 64 + (((4 + lhi) ^ (l15 & 7)) << 3);
  const int vB  = lhi * 1024 + wn * 512 + l15 * 8;

  f4 acc[4][4];
#pragma unroll
  for (int mf = 0; mf < 4; ++mf)
#pragma unroll
    for (int nf = 0; nf < 4; ++nf)
      acc[mf][nf] = (f4){0.f, 0.f, 0.f, 0.f};

  // Prologue: two tiles in flight; publish tile 0 only (keep tile 1 flying).
  STAGE(0, 0);
  STAGE(1, 1);
  asm volatile("s_waitcnt vmcnt(8)\n\ts_barrier" ::: "memory");
  __builtin_amdgcn_sched_barrier(0);

  for (int kt = 0; kt < 16; ++kt) {
    const int c = kt & 1;
#pragma unroll
    for (int kk = 0; kk < 2; ++kk) {
      h8 af[4], bf[4];
      const int a0 = (kk ? vA1 : vA0);
#pragma unroll
      for (int mf = 0; mf < 4; ++mf)
        af[mf] = *(const h8*)&Asm[c][a0 + mf * 1024];
#pragma unroll
      for (int nf = 0; nf < 4; ++nf)
        bf[nf] = *(const h8*)&Bsm[c][vB + kk * 4096 + nf * 128];
#pragma unroll
      for (int mf = 0; mf < 4; ++mf)
#pragma unroll
        for (int nf = 0; nf < 4; ++nf)
          acc[mf][nf] = __builtin_amdgcn_mfma_f32_16x16x32_f16(af[mf], bf[nf], acc[mf][nf], 0, 0, 0);
    }
    if (kt == 15) break;
    // All waves done READING buf c (lgkm retired by MFMA-use waits; barrier joins).
    asm volatile("s_waitcnt lgkmcnt(0)\n\ts_barrier" ::: "memory");
    __builtin_amdgcn_sched_barrier(0);
    if (kt < 14) {
      STAGE(c, kt + 2);                 // overwrite c with tile kt+2
      // Tile kt+1 ready: outstanding = S(kt+1)[8] + S(kt+2)[8] -> drain to 8.
      asm volatile("s_waitcnt vmcnt(8)\n\ts_barrier" ::: "memory");
    } else {
      // kt == 14: nothing newer in flight; drain S(15) fully.
      asm volatile("s_waitcnt vmcnt(0)\n\ts_barrier" ::: "memory");
    }
    __builtin_amdgcn_sched_barrier(0);
  }

  // Epilogue: e[row] += sum over this wave's 64 cols of fast_tanh(u)*Ve
  float vev[4], biasv[4];
#pragma unroll
  for (int nf = 0; nf < 4; ++nf) {
    int c = nt * 128 + wn * 64 + nf * 16 + l15;
    vev[nf]   = Ve[c];
    biasv[nf] = bias[(size_t)bb * 512 + c];
  }
#pragma unroll
  for (int mf = 0; mf < 4; ++mf) {
#pragma unroll
    for (int j = 0; j < 4; ++j) {
      float s = 0.f;
#pragma unroll
      for (int nf = 0; nf < 4; ++nf)
        s += fast_tanh(acc[mf][nf][j] + biasv[nf]) * vev[nf];
#pragma unroll
      for (int m = 1; m < 16; m <<= 1) s += __shfl_xor(s, m, 64);
      if (l15 == 0) atomicAdd(&e[row0 + wm * 64 + mf * 16 + lhi * 4 + j], s);
    }
  }
}

// ---------------------------------------------------------------------------
// Fused softmax + context. Block = (b, sc): row softmax (redundant x4, cheap)
// then context partial for s-chunk sc. 512 blocks x 512 threads.
// ---------------------------------------------------------------------------
__global__ __launch_bounds__(512)
void smax_ctx_kernel(const _Float16* __restrict__ hF, const float* __restrict__ e,
                     float* __restrict__ out) {
  const int b  = blockIdx.x >> 2;
  const int sc = blockIdx.x & 3;
  const int t  = threadIdx.x;
  __shared__ float al[512];
  __shared__ float redm[8], reds[8];
  float v = e[(size_t)b * 512 + t];
  float m = v;
#pragma unroll
  for (int d = 1; d < 64; d <<= 1) m = fmaxf(m, __shfl_xor(m, d, 64));
  if ((t & 63) == 0) redm[t >> 6] = m;
  __syncthreads();
  m = redm[0];
#pragma unroll
  for (int i = 1; i < 8; ++i) m = fmaxf(m, redm[i]);
  float ev = __expf(v - m);
  al[t] = ev;
  float s = ev;
#pragma unroll
  for (int d = 1; d < 64; d <<= 1) s += __shfl_xor(s, d, 64);
  if ((t & 63) == 0) reds[t >> 6] = s;
  __syncthreads();                     // al[] and reds[] both published
  s = reds[0];
#pragma unroll
  for (int i = 1; i < 8; ++i) s += reds[i];
  const float inv = 1.0f / s;
  const _Float16* hp = hF + ((size_t)b * 512 + sc * 128) * 512 + t;
  float acc = 0.f;
#pragma unroll 4
  for (int q = 0; q < 128; ++q) acc += al[sc * 128 + q] * (float)hp[(size_t)q * 512];
  atomicAdd(&out[(size_t)b * 512 + t], acc * inv);
}

// ---------------------------------------------------------------------------
extern "C" void kernel_launch(void* const* d_in, const int* in_sizes, int n_in,
                              void* d_out, int out_size, void* d_ws, size_t ws_size,
                              hipStream_t stream) {
  const float* h  = (const float*)d_in[0];
  const float* x  = (const float*)d_in[1];
  const float* Ve = (const float*)d_in[2];
  const float* U1 = (const float*)d_in[3];
  const float* U2 = (const float*)d_in[4];
  float* out = (float*)d_out;

  const size_t MB = 1u << 20;
  if (ws_size < 130 * MB) return;   // harness provides >=130MB (verified R6)

  // ws: hF 64MB | xF 64MB | Bimg 1MB | bias 256KB | e 256KB
  _Float16* hF   = (_Float16*)d_ws;
  _Float16* xF   = (_Float16*)((char*)d_ws + 64 * MB);
  _Float16* Bimg = (_Float16*)((char*)d_ws + 128 * MB);
  float*    bias = (float*)((char*)d_ws + 129 * MB);
  float*    e    = (float*)((char*)d_ws + 129 * MB + 256 * 1024);

  hipMemsetAsync(e, 0, 65536 * sizeof(float), stream);
  hipMemsetAsync(d_out, 0, 65536 * sizeof(float), stream);

  cvt_kernel<<<4096, 256, 0, stream>>>(h, hF, 4194304);
  cvt_kernel<<<4096, 256, 0, stream>>>(x, xF, 4194304);
  bsetup2_kernel<<<256, 256, 0, stream>>>(U1, U2, Bimg);
  bias_kernel<<<128, 256, 0, stream>>>(h, U1, bias);
  gemm3_kernel<<<2048, 256, 0, stream>>>(hF, xF, Bimg, bias, Ve, e);
  smax_ctx_kernel<<<512, 512, 0, stream>>>(hF, e, out);
}